// Round 1
// baseline (180.197 us; speedup 1.0000x reference)
//
#include <hip/hip_runtime.h>
#include <stdint.h>

typedef unsigned short u16t;
typedef unsigned int   u32t;
typedef _Float16       h16;
typedef __attribute__((ext_vector_type(2))) _Float16 h16x2;
typedef __attribute__((ext_vector_type(8))) short    short8;
typedef __attribute__((ext_vector_type(4))) float    f32x4;

#if defined(__has_builtin)
#if __has_builtin(__builtin_amdgcn_fdot2)
#define HAVE_DOT2 1
#endif
#endif

__device__ __forceinline__ float dot2h(u32t a, u32t b, float c){
#ifdef HAVE_DOT2
  return __builtin_amdgcn_fdot2(__builtin_bit_cast(h16x2, a),
                                __builtin_bit_cast(h16x2, b), c, false);
#else
  h16x2 ha = __builtin_bit_cast(h16x2, a), hb = __builtin_bit_cast(h16x2, b);
  return c + (float)ha[0]*(float)hb[0] + (float)ha[1]*(float)hb[1];
#endif
}

__device__ __forceinline__ float bf2f(u16t h){
  union { u32t u; float f; } c; c.u = ((u32t)h) << 16; return c.f;
}
// round-half-up f32 pair -> packed bf16 (2 adds + 1 v_perm)
__device__ __forceinline__ u32t pk2bf(float a, float b){
  u32t ua = __builtin_bit_cast(u32t, a) + 0x8000u;
  u32t ub = __builtin_bit_cast(u32t, b) + 0x8000u;
  return __builtin_amdgcn_perm(ub, ua, 0x07060302u);
}
__device__ __forceinline__ u32t pk2h(float a, float b){
  h16x2 h = { (h16)a, (h16)b };
  return __builtin_bit_cast(u32t, h);
}

// dtype-generic helpers ----------------------------------------------------
template<bool BF>
__device__ __forceinline__ float ldv(const void* p, size_t i){
  if constexpr (BF) return bf2f(((const u16t*)p)[i]);
  else              return ((const float*)p)[i];
}
template<bool BF>
__device__ __forceinline__ void ld8(const void* p, size_t i, float* v){
  if constexpr (BF){
    uint4 u = *(const uint4*)((const u16t*)p + i);
    const u32t a[4] = {u.x, u.y, u.z, u.w};
#pragma unroll
    for (int d = 0; d < 4; ++d){
      v[2*d]   = bf2f((u16t)(a[d] & 0xffffu));
      v[2*d+1] = bf2f((u16t)(a[d] >> 16));
    }
  } else {
    const float4* q = (const float4*)((const float*)p + i);
    float4 A = q[0], B = q[1];
    v[0]=A.x; v[1]=A.y; v[2]=A.z; v[3]=A.w;
    v[4]=B.x; v[5]=B.y; v[6]=B.z; v[7]=B.w;
  }
}
// 8 elements -> 4 packed bf16 pairs
template<bool BF>
__device__ __forceinline__ void ld8pk(const void* p, size_t i, u32t* dst){
  if constexpr (BF){
    uint4 u = *(const uint4*)((const u16t*)p + i);
    dst[0]=u.x; dst[1]=u.y; dst[2]=u.z; dst[3]=u.w;
  } else {
    const float4* q = (const float4*)((const float*)p + i);
    float4 A = q[0], B = q[1];
    dst[0] = pk2bf(A.x, A.y); dst[1] = pk2bf(A.z, A.w);
    dst[2] = pk2bf(B.x, B.y); dst[3] = pk2bf(B.z, B.w);
  }
}

// inline per-wave dtype probe on x[0:128] (wave-uniform, no barrier)
__device__ __forceinline__ bool probe_bf(const void* xv){
  const u16t* p = (const u16t*)xv;
  const int lane = threadIdx.x & 63;
  const u16t h0 = p[lane], h1 = p[lane + 64];
  const int e0 = (h0 >> 7) & 0xff, e1 = (h1 >> 7) & 0xff;
  unsigned long long b0 = __ballot(e0 >= 90 && e0 <= 150);
  unsigned long long b1 = __ballot(e1 >= 90 && e1 <= 150);
  return (__popcll(b0) + __popcll(b1)) >= 104;
}

// async 16B global -> LDS (wave-uniform LDS base + lane*16 dest)
__device__ __forceinline__ void gld_lds16(const void* g, void* l){
  __builtin_amdgcn_global_load_lds(
      (const __attribute__((address_space(1))) u32t*)g,
      (__attribute__((address_space(3))) u32t*)l, 16, 0, 0);
}

// ---------------------------------------------------------------------------
// Fused pre-pass, grid 384 x 1024:
//   bid 0..255 : y -> y_t transpose (bf16, rotation-swizzled LDS image)
//   bid 256..319: conv1 + dw3x3 + BN + StarReLU -> t2 (4 channels/block)
//   bid 320..383: W_base -> permuted packed-f16 wbh2
// ---------------------------------------------------------------------------

// y_t slab (64KB per (b,i,jp)): row = g*64 + p*8 + q  (512 B/row),
// octet o_oct at phys = (o_oct + row) & 31 -> identical to k_main LDS image.
template<bool BF>
__device__ __forceinline__ void trans_body(const void* y, u16t* yt, int bid){
  const int b = bid >> 7, i = (bid >> 3) & 15, jp = bid & 7;
  const int tid   = threadIdx.x;
  const int o_oct = tid & 31, p = (tid >> 5) & 7, g = (tid >> 8) & 1, rh = tid >> 9;
  u32t Rp[4][4];
#pragma unroll
  for (int r4 = 0; r4 < 4; ++r4){
    const int r = rh * 4 + r4;
    const size_t idx = (((size_t)(b * 256 + o_oct * 8 + r)) * 128 + (i * 8 + p)) * 128
                     + (jp * 2 + g) * 8;
    ld8pk<BF>(y, idx, Rp[r4]);
  }
  u16t* slab = yt + (size_t)bid * 32768;
#pragma unroll
  for (int q = 0; q < 8; ++q){
    const int d = q >> 1, h = q & 1;
    const u32t lo0 = Rp[0][d], hi0 = Rp[1][d];
    const u32t lo1 = Rp[2][d], hi1 = Rp[3][d];
    const u32t c0 = h ? ((lo0 >> 16)     | (hi0 & 0xffff0000u))
                      : ((lo0 & 0xffffu) | (hi0 << 16));
    const u32t c1 = h ? ((lo1 >> 16)     | (hi1 & 0xffff0000u))
                      : ((lo1 & 0xffffu) | (hi1 << 16));
    const int row  = g * 64 + p * 8 + q;
    const int phys = (o_oct + row) & 31;
    *(uint2*)(slab + (size_t)row * 256 + phys * 8 + rh * 4) = make_uint2(c0, c1);
  }
}

template<bool BF>
__device__ __forceinline__ void pre12_body(
    const void* x, const void* w, const void* bias,
    const void* dww, const void* dwb,
    const void* bng, const void* bnb, const void* bnm, const void* bnv,
    const void* s1s, const void* s1b, float* t2, float (*ts)[256], int bq)
{
  const int b = bq >> 5, cq = bq & 31;
  const int cl = threadIdx.x >> 8, ij = threadIdx.x & 255;
  const int c = cq * 4 + cl;
  const int i = ij >> 4, j = ij & 15;
  float a0 = ldv<BF>(bias, c);
  const size_t xb = (size_t)b * 65536 + ij;
#pragma unroll 8
  for (int k = 0; k < 256; ++k)
    a0 += ldv<BF>(x, xb + (size_t)k * 256) * ldv<BF>(w, (size_t)c * 256 + k);
  ts[cl][ij] = a0;
  __syncthreads();
  float s = ldv<BF>(dwb, c);
#pragma unroll
  for (int di = 0; di < 3; ++di){
    const int ii = i + di - 1;
    if (ii < 0 || ii > 15) continue;
#pragma unroll
    for (int dj = 0; dj < 3; ++dj){
      const int jj = j + dj - 1;
      if (jj < 0 || jj > 15) continue;
      s += ts[cl][ii * 16 + jj] * ldv<BF>(dww, c * 9 + di * 3 + dj);
    }
  }
  const float v = ldv<BF>(bng, c) * (s - ldv<BF>(bnm, c)) *
                  rsqrtf(ldv<BF>(bnv, c) + 1e-5f) + ldv<BF>(bnb, c);
  const float r = fmaxf(v, 0.0f);
  t2[((size_t)b * 128 + c) * 256 + ij] = ldv<BF>(s1s, 0) * r * r + ldv<BF>(s1b, 0);
}

template<bool BF>
__device__ __forceinline__ void prew_body(const void* wb, uint4* wbh2, int pb){
  const int t = pb * 1024 + threadIdx.x;
  const int e = t & 255, o = t >> 8;
  float v[8];
  ld8<BF>(wb, ((size_t)e * 256 + o) * 8, v);
  wbh2[(size_t)o * 256 + e] = make_uint4(pk2h(v[0], v[1]), pk2h(v[2], v[3]),
                                         pk2h(v[4], v[5]), pk2h(v[6], v[7]));
}

__global__ __launch_bounds__(1024) void k_fused(
    const void* x, const void* y,
    const void* w1, const void* b1, const void* dww, const void* dwb,
    const void* bng, const void* bnb, const void* bnm, const void* bnv,
    const void* s1s, const void* s1b, const void* wb,
    float* t2, uint4* wbh2, u16t* yt)
{
  __shared__ float ts[4][256];
  const bool bf = probe_bf(x);
  const int bid = blockIdx.x;
  if (bid < 256){
    if (bf) trans_body<true >(y, yt, bid);
    else    trans_body<false>(y, yt, bid);
  } else if (bid < 320){
    if (bf) pre12_body<true >(x,w1,b1,dww,dwb,bng,bnb,bnm,bnv,s1s,s1b,t2,ts,bid-256);
    else    pre12_body<false>(x,w1,b1,dww,dwb,bng,bnb,bnm,bnv,s1s,s1b,t2,ts,bid-256);
  } else {
    if (bf) prew_body<true >(wb, wbh2, bid - 320);
    else    prew_body<false>(wb, wbh2, bid - 320);
  }
}

// ---------------------------------------------------------------------------
// Main hyper-GEMM: grid 256 = (b, i, j-pair), block 1024 = 16 waves.
// Wave w owns e-tile [w*16, w*16+16) -> full E=256 per block (no y re-fetch).
// Stage: 64KB y_t slab -> LDS via global_load_lds dwordx4 (coalesced, linear
// dest; swizzle pre-baked in y_t). channel_expand (pre3) inlined on 16 lanes
// under the staging latency. One barrier total.
// ---------------------------------------------------------------------------
template<bool BF>
__device__ __forceinline__ void main_body(
    const float* t2, const void* cew, const void* ceb,
    const void* s2s, const void* s2b,
    const u16t* yt, const uint4* wbh2, float* out, u16t* smem)
{
  const int bid = blockIdx.x;
  const int b = bid >> 7, i = (bid >> 3) & 15, j0 = (bid & 7) * 2;
  const int tid = threadIdx.x;
  const int wv = tid >> 6, lane = tid & 63;

  // ---- async stage: y_t slab (LDS image) -> LDS, fully coalesced
  {
    const char* src = (const char*)yt + (size_t)bid * 65536 + wv * 4096 + lane * 16;
    char* dst = (char*)smem + wv * 4096;
#pragma unroll
    for (int k = 0; k < 4; ++k)
      gld_lds16(src + k * 1024, dst + k * 1024);
  }

  float* wds = (float*)(smem + 32768);   // 16 floats after the 64KB tile

  // ---- inline channel_expand + StarReLU for this block's 2 columns
  if (tid < 16){
    const int g = tid >> 3, f = tid & 7;
    const int ij = i * 16 + j0 + g;
    float a = ldv<BF>(ceb, f);
    const float* tp = t2 + (size_t)b * 32768 + ij;
#pragma unroll 8
    for (int c = 0; c < 128; ++c)
      a += tp[(size_t)c * 256] * ldv<BF>(cew, (size_t)f * 128 + c);
    const float r = fmaxf(a, 0.0f);
    wds[tid] = ldv<BF>(s2s, 0) * r * r + ldv<BF>(s2b, 0);
  }

  const int l15 = lane & 15, l4 = lane >> 4;
  const int e0  = wv * 16;

  // W loads: o = ks*32 + l4*8 + r ; idx = o*256 + e0 + l15 (coalesced in l15)
  const uint4* wrow = wbh2 + (size_t)(l4 * 8) * 256 + e0 + l15;

  uint4 Wb[2][8];
#pragma unroll
  for (int r = 0; r < 8; ++r) Wb[0][r] = wrow[(size_t)r * 256];

  f32x4 acc[2][4];
#pragma unroll
  for (int g = 0; g < 2; ++g)
#pragma unroll
    for (int nt = 0; nt < 4; ++nt)
      acc[g][nt] = (f32x4){0.f, 0.f, 0.f, 0.f};

  __syncthreads();   // the only barrier (drains gload_lds + Wb[0] + wds)

  // wdec packed f16 pairs for both g
  u32t wdp[2][4];
#pragma unroll
  for (int g = 0; g < 2; ++g)
#pragma unroll
    for (int d = 0; d < 4; ++d)
      wdp[g][d] = pk2h(wds[g * 8 + 2 * d], wds[g * 8 + 2 * d + 1]);

#pragma unroll
  for (int ks = 0; ks < 8; ++ks){
    const int cur = ks & 1;
    if (ks < 7){
#pragma unroll
      for (int r = 0; r < 8; ++r)
        Wb[cur ^ 1][r] = wrow[(size_t)((ks + 1) * 32 + r) * 256];
    }
    // A-gen: s[g][r] = dot(W[e, o=ks*32+l4*8+r][:], wdec_g)
    float s[2][8];
#pragma unroll
    for (int r = 0; r < 8; ++r){
      const uint4 w4 = Wb[cur][r];
#pragma unroll
      for (int g = 0; g < 2; ++g){
        float t = dot2h(w4.x, wdp[g][0], 0.0f);
        t = dot2h(w4.y, wdp[g][1], t);
        t = dot2h(w4.z, wdp[g][2], t);
        s[g][r] = dot2h(w4.w, wdp[g][3], t);
      }
    }
#pragma unroll
    for (int g = 0; g < 2; ++g){
      u32t a4[4];
#pragma unroll
      for (int d = 0; d < 4; ++d) a4[d] = pk2bf(s[g][2*d], s[g][2*d+1]);
      const short8 af = __builtin_bit_cast(short8, *(uint4*)a4);
#pragma unroll
      for (int nt = 0; nt < 4; ++nt){
        const int row  = g * 64 + nt * 16 + l15;
        const int phys = (ks * 4 + l4 + row) & 31;
        const short8 bfr = *(const short8*)(smem + row * 256 + phys * 8);
        acc[g][nt] = __builtin_amdgcn_mfma_f32_16x16x32_bf16(af, bfr, acc[g][nt], 0, 0, 0);
      }
    }
  }

  // ---- epilogue: C/D layout col=lane&15, row=(lane>>4)*4+reg
#pragma unroll
  for (int g = 0; g < 2; ++g){
#pragma unroll
    for (int nt = 0; nt < 4; ++nt){
      const int col = nt * 16 + l15;
      const int pp = col >> 3, qq = col & 7;
#pragma unroll
      for (int r = 0; r < 4; ++r){
        const int ee = e0 + l4 * 4 + r;
        const size_t oaddr = ((size_t)(b * 256 + ee) * 128 + (i * 8 + pp)) * 128
                           + (j0 + g) * 8 + qq;
        out[oaddr] = acc[g][nt][r];
      }
    }
  }
}
__global__ __launch_bounds__(1024, 4) void k_main(
    const void* x, const float* t2, const void* cew, const void* ceb,
    const void* s2s, const void* s2b,
    const u16t* yt, const uint4* wbh2, float* out)
{
  extern __shared__ __align__(16) u16t smem[];
  if (probe_bf(x)) main_body<true >(t2, cew, ceb, s2s, s2b, yt, wbh2, out, smem);
  else             main_body<false>(t2, cew, ceb, s2s, s2b, yt, wbh2, out, smem);
}

// ---------------------------------------------------------------------------
extern "C" void kernel_launch(void* const* d_in, const int* in_sizes, int n_in,
                              void* d_out, int out_size, void* d_ws, size_t ws_size,
                              hipStream_t stream)
{
  float* t2    = (float*)d_ws;                        // 262144 B
  uint4* wbh2  = (uint4*)((char*)d_ws + 262144);      // 1048576 B
  u16t*  yt    = (u16t*)((char*)d_ws + 1310720);      // 16777216 B (64KB-aligned)

  k_fused<<<dim3(384), dim3(1024), 0, stream>>>(
      d_in[0], d_in[1], d_in[2], d_in[3], d_in[4], d_in[5], d_in[6], d_in[7],
      d_in[8], d_in[9], d_in[10], d_in[11], d_in[16], t2, wbh2, yt);

  const int lds_bytes = 65536 + 64;                   // y tile + 16 wdec floats
  hipFuncSetAttribute((const void*)k_main,
                      hipFuncAttributeMaxDynamicSharedMemorySize, lds_bytes);
  k_main<<<dim3(256), dim3(1024), lds_bytes, stream>>>(
      d_in[0], t2, d_in[12], d_in[13], d_in[14], d_in[15], yt, wbh2, (float*)d_out);
}

// Round 2
// 155.878 us; speedup vs baseline: 1.1560x; 1.1560x over previous
//
#include <hip/hip_runtime.h>
#include <stdint.h>

typedef unsigned short u16t;
typedef unsigned int   u32t;
typedef _Float16       h16;
typedef __attribute__((ext_vector_type(2))) _Float16 h16x2;
typedef __attribute__((ext_vector_type(8))) short    short8;
typedef __attribute__((ext_vector_type(4))) float    f32x4;

#if defined(__has_builtin)
#if __has_builtin(__builtin_amdgcn_fdot2)
#define HAVE_DOT2 1
#endif
#endif

__device__ __forceinline__ float dot2h(u32t a, u32t b, float c){
#ifdef HAVE_DOT2
  return __builtin_amdgcn_fdot2(__builtin_bit_cast(h16x2, a),
                                __builtin_bit_cast(h16x2, b), c, false);
#else
  h16x2 ha = __builtin_bit_cast(h16x2, a), hb = __builtin_bit_cast(h16x2, b);
  return c + (float)ha[0]*(float)hb[0] + (float)ha[1]*(float)hb[1];
#endif
}

__device__ __forceinline__ float bf2f(u16t h){
  union { u32t u; float f; } c; c.u = ((u32t)h) << 16; return c.f;
}
// round-half-up f32 pair -> packed bf16 (a -> low16, b -> high16)
__device__ __forceinline__ u32t pk2bf(float a, float b){
  u32t ua = __builtin_bit_cast(u32t, a) + 0x8000u;
  u32t ub = __builtin_bit_cast(u32t, b) + 0x8000u;
  return __builtin_amdgcn_perm(ub, ua, 0x07060302u);
}
__device__ __forceinline__ u32t pk2h(float a, float b){
  h16x2 h = { (h16)a, (h16)b };
  return __builtin_bit_cast(u32t, h);
}

// dtype-generic helpers ----------------------------------------------------
template<bool BF>
__device__ __forceinline__ float ldv(const void* p, size_t i){
  if constexpr (BF) return bf2f(((const u16t*)p)[i]);
  else              return ((const float*)p)[i];
}
template<bool BF>
__device__ __forceinline__ void ld8(const void* p, size_t i, float* v){
  if constexpr (BF){
    uint4 u = *(const uint4*)((const u16t*)p + i);
    const u32t a[4] = {u.x, u.y, u.z, u.w};
#pragma unroll
    for (int d = 0; d < 4; ++d){
      v[2*d]   = bf2f((u16t)(a[d] & 0xffffu));
      v[2*d+1] = bf2f((u16t)(a[d] >> 16));
    }
  } else {
    const float4* q = (const float4*)((const float*)p + i);
    float4 A = q[0], B = q[1];
    v[0]=A.x; v[1]=A.y; v[2]=A.z; v[3]=A.w;
    v[4]=B.x; v[5]=B.y; v[6]=B.z; v[7]=B.w;
  }
}

// inline per-wave dtype probe on x[0:128] (wave-uniform, no barrier)
__device__ __forceinline__ bool probe_bf(const void* xv){
  const u16t* p = (const u16t*)xv;
  const int lane = threadIdx.x & 63;
  const u16t h0 = p[lane], h1 = p[lane + 64];
  const int e0 = (h0 >> 7) & 0xff, e1 = (h1 >> 7) & 0xff;
  unsigned long long b0 = __ballot(e0 >= 90 && e0 <= 150);
  unsigned long long b1 = __ballot(e1 >= 90 && e1 <= 150);
  return (__popcll(b0) + __popcll(b1)) >= 104;
}

// ---------------------------------------------------------------------------
// Pre-pass, grid 128 x 1024:
//   bid 0..63 : conv1 + dw3x3 + BN + StarReLU -> t2 (4 channels/block)
//   bid 64..127: W_base -> permuted packed-f16 wbh2
// ---------------------------------------------------------------------------
template<bool BF>
__device__ __forceinline__ void pre12_body(
    const void* x, const void* w, const void* bias,
    const void* dww, const void* dwb,
    const void* bng, const void* bnb, const void* bnm, const void* bnv,
    const void* s1s, const void* s1b, float* t2, float (*ts)[256], int bq)
{
  const int b = bq >> 5, cq = bq & 31;
  const int cl = threadIdx.x >> 8, ij = threadIdx.x & 255;
  const int c = cq * 4 + cl;
  const int i = ij >> 4, j = ij & 15;
  float a0 = ldv<BF>(bias, c);
  const size_t xb = (size_t)b * 65536 + ij;
#pragma unroll 8
  for (int k = 0; k < 256; ++k)
    a0 += ldv<BF>(x, xb + (size_t)k * 256) * ldv<BF>(w, (size_t)c * 256 + k);
  ts[cl][ij] = a0;
  __syncthreads();
  float s = ldv<BF>(dwb, c);
#pragma unroll
  for (int di = 0; di < 3; ++di){
    const int ii = i + di - 1;
    if (ii < 0 || ii > 15) continue;
#pragma unroll
    for (int dj = 0; dj < 3; ++dj){
      const int jj = j + dj - 1;
      if (jj < 0 || jj > 15) continue;
      s += ts[cl][ii * 16 + jj] * ldv<BF>(dww, c * 9 + di * 3 + dj);
    }
  }
  const float v = ldv<BF>(bng, c) * (s - ldv<BF>(bnm, c)) *
                  rsqrtf(ldv<BF>(bnv, c) + 1e-5f) + ldv<BF>(bnb, c);
  const float r = fmaxf(v, 0.0f);
  t2[((size_t)b * 128 + c) * 256 + ij] = ldv<BF>(s1s, 0) * r * r + ldv<BF>(s1b, 0);
}

template<bool BF>
__device__ __forceinline__ void prew_body(const void* wb, uint4* wbh2, int pb){
  const int t = pb * 1024 + threadIdx.x;
  const int e = t & 255, o = t >> 8;
  float v[8];
  ld8<BF>(wb, ((size_t)e * 256 + o) * 8, v);
  wbh2[(size_t)o * 256 + e] = make_uint4(pk2h(v[0], v[1]), pk2h(v[2], v[3]),
                                         pk2h(v[4], v[5]), pk2h(v[6], v[7]));
}

__global__ __launch_bounds__(1024) void k_fused(
    const void* x,
    const void* w1, const void* b1, const void* dww, const void* dwb,
    const void* bng, const void* bnb, const void* bnm, const void* bnv,
    const void* s1s, const void* s1b, const void* wb,
    float* t2, uint4* wbh2)
{
  __shared__ float ts[4][256];
  const bool bf = probe_bf(x);
  const int bid = blockIdx.x;
  if (bid < 64){
    if (bf) pre12_body<true >(x,w1,b1,dww,dwb,bng,bnb,bnm,bnv,s1s,s1b,t2,ts,bid);
    else    pre12_body<false>(x,w1,b1,dww,dwb,bng,bnb,bnm,bnv,s1s,s1b,t2,ts,bid);
  } else {
    if (bf) prew_body<true >(wb, wbh2, bid - 64);
    else    prew_body<false>(wb, wbh2, bid - 64);
  }
}

// ---------------------------------------------------------------------------
// Main hyper-GEMM: grid 256 = (b, i, j-pair), block 1024 = 16 waves.
// Wave w owns e-tile [w*16, w*16+16) -> full E=256 per block (y read ONCE,
// directly from global, coalesced). Staging = in-register f32->bf16 convert +
// scattered 4B LDS writes into the rotated LDS image (<=4-way bank alias).
// channel_expand inlined on 64 lanes (shfl-reduced). One barrier total.
// ---------------------------------------------------------------------------
template<bool BF>
__device__ __forceinline__ void main_body(
    const void* y, const float* t2, const void* cew, const void* ceb,
    const void* s2s, const void* s2b,
    const uint4* wbh2, float* out, u16t* smem)
{
  const int bid = blockIdx.x;
  const int b = bid >> 7, i = (bid >> 3) & 15, jp = bid & 7, j0 = jp * 2;
  const int tid = threadIdx.x;
  const int wv = tid >> 6, lane = tid & 63;

  // ---- staging-transpose: y[o][h][w] -> LDS [row(p,q,g)][o octets rotated]
  // lanes sweep w -> every global load instruction = 16 fully-used 64B lines.
  {
    const int w4 = tid & 3, p = (tid >> 2) & 7, opq = tid >> 5;   // opq 0..31
    u32t pk[4][4];
#pragma unroll
    for (int r = 0; r < 4; ++r){
      const int o = (r * 32 + opq) * 2;                            // even o
      const size_t base = (((size_t)(b * 256 + o) * 128) + i * 8 + p) * 128
                        + jp * 16 + w4 * 4;
      if constexpr (BF){
        const u16t* yp = (const u16t*)y;
        const uint2 u0 = *(const uint2*)(yp + base);               // o,   w4*4..+4
        const uint2 u1 = *(const uint2*)(yp + base + 16384);       // o+1
        pk[r][0] = (u0.x & 0xffffu) | (u1.x << 16);
        pk[r][1] = (u0.x >> 16)     | (u1.x & 0xffff0000u);
        pk[r][2] = (u0.y & 0xffffu) | (u1.y << 16);
        pk[r][3] = (u0.y >> 16)     | (u1.y & 0xffff0000u);
      } else {
        const float* yp = (const float*)y;
        const float4 A = *(const float4*)(yp + base);
        const float4 B = *(const float4*)(yp + base + 16384);
        pk[r][0] = pk2bf(A.x, B.x); pk[r][1] = pk2bf(A.y, B.y);
        pk[r][2] = pk2bf(A.z, B.z); pk[r][3] = pk2bf(A.w, B.w);
      }
    }
#pragma unroll
    for (int r = 0; r < 4; ++r){
      const int o  = (r * 32 + opq) * 2;
      const int oc = o >> 3, osub = o & 7;                         // osub in {0,2,4,6}
#pragma unroll
      for (int k = 0; k < 4; ++k){
        const int w_l  = w4 * 4 + k;
        const int row  = (w_l >> 3) * 64 + p * 8 + (w_l & 7);
        const int phys = (oc + row) & 31;                          // rotation swizzle
        *(u32t*)(smem + row * 256 + phys * 8 + osub) = pk[r][k];
      }
    }
  }

  float* wds = (float*)(smem + 32768);   // 16 floats after the 64KB tile

  // ---- inline channel_expand + StarReLU, 64-lane parallel + shfl reduce
  if (tid < 64){
    const int g = (tid >> 5) & 1, f = (tid >> 2) & 7, cq = tid & 3;
    const int ij = i * 16 + j0 + g;
    const float* tp = t2 + (size_t)b * 32768 + ij;
    float a = 0.0f;
#pragma unroll 8
    for (int c = cq; c < 128; c += 4)
      a += tp[(size_t)c * 256] * ldv<BF>(cew, (size_t)f * 128 + c);
    a += __shfl_xor(a, 1);
    a += __shfl_xor(a, 2);
    if (cq == 0){
      const float tot = a + ldv<BF>(ceb, f);
      const float rr  = fmaxf(tot, 0.0f);
      wds[g * 8 + f] = ldv<BF>(s2s, 0) * rr * rr + ldv<BF>(s2b, 0);
    }
  }

  const int l15 = lane & 15, l4 = lane >> 4;
  const int e0  = wv * 16;

  // W loads: o = ks*32 + l4*8 + r ; idx = o*256 + e0 + l15 (coalesced in l15)
  const uint4* wrow = wbh2 + (size_t)(l4 * 8) * 256 + e0 + l15;

  uint4 Wb[2][8];
#pragma unroll
  for (int r = 0; r < 8; ++r) Wb[0][r] = wrow[(size_t)r * 256];

  f32x4 acc[2][4];
#pragma unroll
  for (int g = 0; g < 2; ++g)
#pragma unroll
    for (int nt = 0; nt < 4; ++nt)
      acc[g][nt] = (f32x4){0.f, 0.f, 0.f, 0.f};

  __syncthreads();   // the only barrier (drains ds_writes + Wb[0] + wds)

  // wdec packed f16 pairs for both g
  u32t wdp[2][4];
#pragma unroll
  for (int g = 0; g < 2; ++g)
#pragma unroll
    for (int d = 0; d < 4; ++d)
      wdp[g][d] = pk2h(wds[g * 8 + 2 * d], wds[g * 8 + 2 * d + 1]);

#pragma unroll
  for (int ks = 0; ks < 8; ++ks){
    const int cur = ks & 1;
    if (ks < 7){
#pragma unroll
      for (int r = 0; r < 8; ++r)
        Wb[cur ^ 1][r] = wrow[(size_t)((ks + 1) * 32 + r) * 256];
    }
    // A-gen: s[g][r] = dot(W[e, o=ks*32+l4*8+r][:], wdec_g)
    float s[2][8];
#pragma unroll
    for (int r = 0; r < 8; ++r){
      const uint4 w4 = Wb[cur][r];
#pragma unroll
      for (int g = 0; g < 2; ++g){
        float t = dot2h(w4.x, wdp[g][0], 0.0f);
        t = dot2h(w4.y, wdp[g][1], t);
        t = dot2h(w4.z, wdp[g][2], t);
        s[g][r] = dot2h(w4.w, wdp[g][3], t);
      }
    }
#pragma unroll
    for (int g = 0; g < 2; ++g){
      u32t a4[4];
#pragma unroll
      for (int d = 0; d < 4; ++d) a4[d] = pk2bf(s[g][2*d], s[g][2*d+1]);
      const short8 af = __builtin_bit_cast(short8, *(uint4*)a4);
#pragma unroll
      for (int nt = 0; nt < 4; ++nt){
        const int row  = g * 64 + nt * 16 + l15;
        const int phys = (ks * 4 + l4 + row) & 31;
        const short8 bfr = *(const short8*)(smem + row * 256 + phys * 8);
        acc[g][nt] = __builtin_amdgcn_mfma_f32_16x16x32_bf16(af, bfr, acc[g][nt], 0, 0, 0);
      }
    }
  }

  // ---- epilogue: C/D layout col=lane&15, row=(lane>>4)*4+reg
#pragma unroll
  for (int g = 0; g < 2; ++g){
#pragma unroll
    for (int nt = 0; nt < 4; ++nt){
      const int col = nt * 16 + l15;
      const int pp = col >> 3, qq = col & 7;
#pragma unroll
      for (int r = 0; r < 4; ++r){
        const int ee = e0 + l4 * 4 + r;
        const size_t oaddr = ((size_t)(b * 256 + ee) * 128 + (i * 8 + pp)) * 128
                           + (j0 + g) * 8 + qq;
        out[oaddr] = acc[g][nt][r];
      }
    }
  }
}
__global__ __launch_bounds__(1024, 2) void k_main(
    const void* x, const void* y, const float* t2, const void* cew, const void* ceb,
    const void* s2s, const void* s2b,
    const uint4* wbh2, float* out)
{
  extern __shared__ __align__(16) u16t smem[];
  if (probe_bf(x)) main_body<true >(y, t2, cew, ceb, s2s, s2b, wbh2, out, smem);
  else             main_body<false>(y, t2, cew, ceb, s2s, s2b, wbh2, out, smem);
}

// ---------------------------------------------------------------------------
extern "C" void kernel_launch(void* const* d_in, const int* in_sizes, int n_in,
                              void* d_out, int out_size, void* d_ws, size_t ws_size,
                              hipStream_t stream)
{
  float* t2    = (float*)d_ws;                        // 262144 B
  uint4* wbh2  = (uint4*)((char*)d_ws + 262144);      // 1048576 B

  k_fused<<<dim3(128), dim3(1024), 0, stream>>>(
      d_in[0], d_in[2], d_in[3], d_in[4], d_in[5], d_in[6], d_in[7],
      d_in[8], d_in[9], d_in[10], d_in[11], d_in[16], t2, wbh2);

  const int lds_bytes = 65536 + 64;                   // y tile + 16 wdec floats
  hipFuncSetAttribute((const void*)k_main,
                      hipFuncAttributeMaxDynamicSharedMemorySize, lds_bytes);
  k_main<<<dim3(256), dim3(1024), lds_bytes, stream>>>(
      d_in[0], d_in[1], t2, d_in[12], d_in[13], d_in[14], d_in[15],
      wbh2, (float*)d_out);
}

// Round 3
// 154.617 us; speedup vs baseline: 1.1654x; 1.0082x over previous
//
#include <hip/hip_runtime.h>
#include <stdint.h>

typedef unsigned short u16t;
typedef unsigned int   u32t;
typedef _Float16       h16;
typedef __attribute__((ext_vector_type(2))) _Float16 h16x2;
typedef __attribute__((ext_vector_type(8))) short    short8;
typedef __attribute__((ext_vector_type(4))) float    f32x4;

#if defined(__has_builtin)
#if __has_builtin(__builtin_amdgcn_fdot2)
#define HAVE_DOT2 1
#endif
#endif

__device__ __forceinline__ float dot2h(u32t a, u32t b, float c){
#ifdef HAVE_DOT2
  return __builtin_amdgcn_fdot2(__builtin_bit_cast(h16x2, a),
                                __builtin_bit_cast(h16x2, b), c, false);
#else
  h16x2 ha = __builtin_bit_cast(h16x2, a), hb = __builtin_bit_cast(h16x2, b);
  return c + (float)ha[0]*(float)hb[0] + (float)ha[1]*(float)hb[1];
#endif
}

__device__ __forceinline__ float bf2f(u16t h){
  union { u32t u; float f; } c; c.u = ((u32t)h) << 16; return c.f;
}
// round-half-up f32 pair -> packed bf16 (a -> low16, b -> high16)
__device__ __forceinline__ u32t pk2bf(float a, float b){
  u32t ua = __builtin_bit_cast(u32t, a) + 0x8000u;
  u32t ub = __builtin_bit_cast(u32t, b) + 0x8000u;
  return __builtin_amdgcn_perm(ub, ua, 0x07060302u);
}
__device__ __forceinline__ u32t pk2h(float a, float b){
  h16x2 h = { (h16)a, (h16)b };
  return __builtin_bit_cast(u32t, h);
}

// dtype-generic helpers ----------------------------------------------------
template<bool BF>
__device__ __forceinline__ float ldv(const void* p, size_t i){
  if constexpr (BF) return bf2f(((const u16t*)p)[i]);
  else              return ((const float*)p)[i];
}
template<bool BF>
__device__ __forceinline__ void ld8(const void* p, size_t i, float* v){
  if constexpr (BF){
    uint4 u = *(const uint4*)((const u16t*)p + i);
    const u32t a[4] = {u.x, u.y, u.z, u.w};
#pragma unroll
    for (int d = 0; d < 4; ++d){
      v[2*d]   = bf2f((u16t)(a[d] & 0xffffu));
      v[2*d+1] = bf2f((u16t)(a[d] >> 16));
    }
  } else {
    const float4* q = (const float4*)((const float*)p + i);
    float4 A = q[0], B = q[1];
    v[0]=A.x; v[1]=A.y; v[2]=A.z; v[3]=A.w;
    v[4]=B.x; v[5]=B.y; v[6]=B.z; v[7]=B.w;
  }
}

// inline per-wave dtype probe on x[0:128] (wave-uniform, no barrier)
__device__ __forceinline__ bool probe_bf(const void* xv){
  const u16t* p = (const u16t*)xv;
  const int lane = threadIdx.x & 63;
  const u16t h0 = p[lane], h1 = p[lane + 64];
  const int e0 = (h0 >> 7) & 0xff, e1 = (h1 >> 7) & 0xff;
  unsigned long long b0 = __ballot(e0 >= 90 && e0 <= 150);
  unsigned long long b1 = __ballot(e1 >= 90 && e1 <= 150);
  return (__popcll(b0) + __popcll(b1)) >= 104;
}

// ---------------------------------------------------------------------------
// Pre-pass, grid 128 x 1024:
//   bid 0..63 : conv1 + dw3x3 + BN + StarReLU -> t2 (4 channels/block)
//   bid 64..127: W_base -> permuted packed-f16 wbh2
// ---------------------------------------------------------------------------
template<bool BF>
__device__ __forceinline__ void pre12_body(
    const void* x, const void* w, const void* bias,
    const void* dww, const void* dwb,
    const void* bng, const void* bnb, const void* bnm, const void* bnv,
    const void* s1s, const void* s1b, float* t2, float (*ts)[256], int bq)
{
  const int b = bq >> 5, cq = bq & 31;
  const int cl = threadIdx.x >> 8, ij = threadIdx.x & 255;
  const int c = cq * 4 + cl;
  const int i = ij >> 4, j = ij & 15;
  float a0 = ldv<BF>(bias, c);
  const size_t xb = (size_t)b * 65536 + ij;
#pragma unroll 8
  for (int k = 0; k < 256; ++k)
    a0 += ldv<BF>(x, xb + (size_t)k * 256) * ldv<BF>(w, (size_t)c * 256 + k);
  ts[cl][ij] = a0;
  __syncthreads();
  float s = ldv<BF>(dwb, c);
#pragma unroll
  for (int di = 0; di < 3; ++di){
    const int ii = i + di - 1;
    if (ii < 0 || ii > 15) continue;
#pragma unroll
    for (int dj = 0; dj < 3; ++dj){
      const int jj = j + dj - 1;
      if (jj < 0 || jj > 15) continue;
      s += ts[cl][ii * 16 + jj] * ldv<BF>(dww, c * 9 + di * 3 + dj);
    }
  }
  const float v = ldv<BF>(bng, c) * (s - ldv<BF>(bnm, c)) *
                  rsqrtf(ldv<BF>(bnv, c) + 1e-5f) + ldv<BF>(bnb, c);
  const float r = fmaxf(v, 0.0f);
  t2[((size_t)b * 128 + c) * 256 + ij] = ldv<BF>(s1s, 0) * r * r + ldv<BF>(s1b, 0);
}

template<bool BF>
__device__ __forceinline__ void prew_body(const void* wb, uint4* wbh2, int pb){
  const int t = pb * 1024 + threadIdx.x;
  const int e = t & 255, o = t >> 8;
  float v[8];
  ld8<BF>(wb, ((size_t)e * 256 + o) * 8, v);
  wbh2[(size_t)o * 256 + e] = make_uint4(pk2h(v[0], v[1]), pk2h(v[2], v[3]),
                                         pk2h(v[4], v[5]), pk2h(v[6], v[7]));
}

__global__ __launch_bounds__(1024) void k_fused(
    const void* x,
    const void* w1, const void* b1, const void* dww, const void* dwb,
    const void* bng, const void* bnb, const void* bnm, const void* bnv,
    const void* s1s, const void* s1b, const void* wb,
    float* t2, uint4* wbh2)
{
  __shared__ float ts[4][256];
  const bool bf = probe_bf(x);
  const int bid = blockIdx.x;
  if (bid < 64){
    if (bf) pre12_body<true >(x,w1,b1,dww,dwb,bng,bnb,bnm,bnv,s1s,s1b,t2,ts,bid);
    else    pre12_body<false>(x,w1,b1,dww,dwb,bng,bnb,bnm,bnv,s1s,s1b,t2,ts,bid);
  } else {
    if (bf) prew_body<true >(wb, wbh2, bid - 64);
    else    prew_body<false>(wb, wbh2, bid - 64);
  }
}

// ---------------------------------------------------------------------------
// Main hyper-GEMM: grid 256 = (b, i, j-pair), block 1024 = 16 waves.
// 4-chunk pipelined schedule: chunk cs = o in [64cs, 64cs+64) maps to K-loop
// phases ks = 2cs, 2cs+1 with DISJOINT rotated LDS regions. Per phase:
//   { issue y loads chunk cs+2  |  ds_write chunk cs+1  |  compute chunk cs }
// with one barrier per phase (4 total). W single-buffered per ks (VGPR<=128).
// ---------------------------------------------------------------------------
template<bool BF>
__device__ __forceinline__ void main_body(
    const void* y, const float* t2, const void* cew, const void* ceb,
    const void* s2s, const void* s2b,
    const uint4* wbh2, float* out, u16t* smem)
{
  const int bid = blockIdx.x;
  const int b = bid >> 7, i = (bid >> 3) & 15, jp = bid & 7, j0 = jp * 2;
  const int tid = threadIdx.x;
  const int wv = tid >> 6, lane = tid & 63;

  // staging thread mapping: w quad, patch row, o-pair index
  const int w4 = tid & 3, p = (tid >> 2) & 7, opq = tid >> 5;   // opq 0..31

  // per-chunk load: 2x float4 (f32) or 2x uint2 (bf16) -> 4 packed u32
  float fA[2][4], fB[2][4];        // f32 path staging regs, [buf][elem]
  u32t  uA[2][2], uB[2][2];        // bf16 path staging regs

  auto issue_loads = [&](int cs, int buf){
    const int o = (cs * 32 + opq) * 2;                           // even o
    const size_t base = (((size_t)(b * 256 + o) * 128) + i * 8 + p) * 128
                      + jp * 16 + w4 * 4;
    if constexpr (BF){
      const u16t* yp = (const u16t*)y;
      const uint2 u0 = *(const uint2*)(yp + base);
      const uint2 u1 = *(const uint2*)(yp + base + 16384);
      uA[buf][0] = u0.x; uA[buf][1] = u0.y;
      uB[buf][0] = u1.x; uB[buf][1] = u1.y;
    } else {
      const float* yp = (const float*)y;
      const float4 A = *(const float4*)(yp + base);
      const float4 B = *(const float4*)(yp + base + 16384);
      fA[buf][0]=A.x; fA[buf][1]=A.y; fA[buf][2]=A.z; fA[buf][3]=A.w;
      fB[buf][0]=B.x; fB[buf][1]=B.y; fB[buf][2]=B.z; fB[buf][3]=B.w;
    }
  };
  auto write_chunk = [&](int cs, int buf){
    u32t pk[4];
    if constexpr (BF){
#pragma unroll
      for (int d = 0; d < 2; ++d){
        const u32t lo = uA[buf][d], hi = uB[buf][d];
        pk[2*d]   = (lo & 0xffffu) | (hi << 16);
        pk[2*d+1] = (lo >> 16)     | (hi & 0xffff0000u);
      }
    } else {
#pragma unroll
      for (int k = 0; k < 4; ++k) pk[k] = pk2bf(fA[buf][k], fB[buf][k]);
    }
    const int o  = (cs * 32 + opq) * 2;
    const int oc = o >> 3, osub = o & 7;                         // osub in {0,2,4,6}
#pragma unroll
    for (int k = 0; k < 4; ++k){
      const int w_l  = w4 * 4 + k;
      const int row  = (w_l >> 3) * 64 + p * 8 + (w_l & 7);
      const int phys = (oc + row) & 31;                          // rotation swizzle
      *(u32t*)(smem + row * 256 + phys * 8 + osub) = pk[k];
    }
  };

  // ---- prologue: chunks 0,1 in flight; channel_expand under the latency
  issue_loads(0, 0);
  issue_loads(1, 1);

  float* wds = (float*)(smem + 32768);   // 16 floats after the 64KB tile

  // inline channel_expand + StarReLU, 64-lane parallel + shfl reduce
  if (tid < 64){
    const int g = (tid >> 5) & 1, f = (tid >> 2) & 7, cq = tid & 3;
    const int ij = i * 16 + j0 + g;
    const float* tp = t2 + (size_t)b * 32768 + ij;
    float a = 0.0f;
#pragma unroll 8
    for (int c = cq; c < 128; c += 4)
      a += tp[(size_t)c * 256] * ldv<BF>(cew, (size_t)f * 128 + c);
    a += __shfl_xor(a, 1);
    a += __shfl_xor(a, 2);
    if (cq == 0){
      const float tot = a + ldv<BF>(ceb, f);
      const float rr  = fmaxf(tot, 0.0f);
      wds[g * 8 + f] = ldv<BF>(s2s, 0) * rr * rr + ldv<BF>(s2b, 0);
    }
  }

  write_chunk(0, 0);   // compiler inserts the vmcnt wait on chunk-0 loads

  const int l15 = lane & 15, l4 = lane >> 4;
  const int e0  = wv * 16;

  // W loads: o = ks*32 + l4*8 + r ; idx = o*256 + e0 + l15 (coalesced in l15)
  const uint4* wrow = wbh2 + (size_t)(l4 * 8) * 256 + e0 + l15;

  f32x4 acc[2][4];
#pragma unroll
  for (int g = 0; g < 2; ++g)
#pragma unroll
    for (int nt = 0; nt < 4; ++nt)
      acc[g][nt] = (f32x4){0.f, 0.f, 0.f, 0.f};

  u32t wdp[2][4];

#pragma unroll
  for (int cs = 0; cs < 4; ++cs){
    __syncthreads();                 // chunk cs (and wds at cs==0) now visible
    if (cs == 0){
#pragma unroll
      for (int g = 0; g < 2; ++g)
#pragma unroll
        for (int d = 0; d < 4; ++d)
          wdp[g][d] = pk2h(wds[g * 8 + 2 * d], wds[g * 8 + 2 * d + 1]);
    }
    if (cs + 2 <= 3) issue_loads(cs + 2, cs & 1);   // reuse freed buffer
    if (cs + 1 <= 3) write_chunk(cs + 1, (cs + 1) & 1);

    // compute phases ks = 2cs, 2cs+1 from chunk cs (single-buffered W)
#pragma unroll
    for (int kh = 0; kh < 2; ++kh){
      const int ks = cs * 2 + kh;
      uint4 Wb[8];
#pragma unroll
      for (int r = 0; r < 8; ++r) Wb[r] = wrow[(size_t)(ks * 32 + r) * 256];
      float s[2][8];
#pragma unroll
      for (int r = 0; r < 8; ++r){
        const uint4 w4r = Wb[r];
#pragma unroll
        for (int g = 0; g < 2; ++g){
          float t = dot2h(w4r.x, wdp[g][0], 0.0f);
          t = dot2h(w4r.y, wdp[g][1], t);
          t = dot2h(w4r.z, wdp[g][2], t);
          s[g][r] = dot2h(w4r.w, wdp[g][3], t);
        }
      }
#pragma unroll
      for (int g = 0; g < 2; ++g){
        u32t a4[4];
#pragma unroll
        for (int d = 0; d < 4; ++d) a4[d] = pk2bf(s[g][2*d], s[g][2*d+1]);
        const short8 af = __builtin_bit_cast(short8, *(uint4*)a4);
#pragma unroll
        for (int nt = 0; nt < 4; ++nt){
          const int row  = g * 64 + nt * 16 + l15;
          const int phys = (ks * 4 + l4 + row) & 31;
          const short8 bfr = *(const short8*)(smem + row * 256 + phys * 8);
          acc[g][nt] = __builtin_amdgcn_mfma_f32_16x16x32_bf16(af, bfr, acc[g][nt], 0, 0, 0);
        }
      }
    }
  }

  // ---- epilogue: C/D layout col=lane&15, row=(lane>>4)*4+reg
#pragma unroll
  for (int g = 0; g < 2; ++g){
#pragma unroll
    for (int nt = 0; nt < 4; ++nt){
      const int col = nt * 16 + l15;
      const int pp = col >> 3, qq = col & 7;
#pragma unroll
      for (int r = 0; r < 4; ++r){
        const int ee = e0 + l4 * 4 + r;
        const size_t oaddr = ((size_t)(b * 256 + ee) * 128 + (i * 8 + pp)) * 128
                           + (j0 + g) * 8 + qq;
        out[oaddr] = acc[g][nt][r];
      }
    }
  }
}
__global__ __launch_bounds__(1024, 4) void k_main(
    const void* x, const void* y, const float* t2, const void* cew, const void* ceb,
    const void* s2s, const void* s2b,
    const uint4* wbh2, float* out)
{
  extern __shared__ __align__(16) u16t smem[];
  if (probe_bf(x)) main_body<true >(y, t2, cew, ceb, s2s, s2b, wbh2, out, smem);
  else             main_body<false>(y, t2, cew, ceb, s2s, s2b, wbh2, out, smem);
}

// ---------------------------------------------------------------------------
extern "C" void kernel_launch(void* const* d_in, const int* in_sizes, int n_in,
                              void* d_out, int out_size, void* d_ws, size_t ws_size,
                              hipStream_t stream)
{
  float* t2    = (float*)d_ws;                        // 262144 B
  uint4* wbh2  = (uint4*)((char*)d_ws + 262144);      // 1048576 B

  k_fused<<<dim3(128), dim3(1024), 0, stream>>>(
      d_in[0], d_in[2], d_in[3], d_in[4], d_in[5], d_in[6], d_in[7],
      d_in[8], d_in[9], d_in[10], d_in[11], d_in[16], t2, wbh2);

  const int lds_bytes = 65536 + 64;                   // y tile + 16 wdec floats
  hipFuncSetAttribute((const void*)k_main,
                      hipFuncAttributeMaxDynamicSharedMemorySize, lds_bytes);
  k_main<<<dim3(256), dim3(1024), lds_bytes, stream>>>(
      d_in[0], d_in[1], t2, d_in[12], d_in[13], d_in[14], d_in[15],
      wbh2, (float*)d_out);
}

// Round 4
// 153.533 us; speedup vs baseline: 1.1737x; 1.0071x over previous
//
#include <hip/hip_runtime.h>
#include <stdint.h>

typedef unsigned short u16t;
typedef unsigned int   u32t;
typedef _Float16       h16;
typedef __attribute__((ext_vector_type(2))) _Float16 h16x2;
typedef __attribute__((ext_vector_type(8))) short    short8;
typedef __attribute__((ext_vector_type(4))) float    f32x4;

#if defined(__has_builtin)
#if __has_builtin(__builtin_amdgcn_fdot2)
#define HAVE_DOT2 1
#endif
#endif

__device__ __forceinline__ float dot2h(u32t a, u32t b, float c){
#ifdef HAVE_DOT2
  return __builtin_amdgcn_fdot2(__builtin_bit_cast(h16x2, a),
                                __builtin_bit_cast(h16x2, b), c, false);
#else
  h16x2 ha = __builtin_bit_cast(h16x2, a), hb = __builtin_bit_cast(h16x2, b);
  return c + (float)ha[0]*(float)hb[0] + (float)ha[1]*(float)hb[1];
#endif
}

__device__ __forceinline__ float bf2f(u16t h){
  union { u32t u; float f; } c; c.u = ((u32t)h) << 16; return c.f;
}
// round-half-up f32 pair -> packed bf16 (a -> low16, b -> high16)
__device__ __forceinline__ u32t pk2bf(float a, float b){
  u32t ua = __builtin_bit_cast(u32t, a) + 0x8000u;
  u32t ub = __builtin_bit_cast(u32t, b) + 0x8000u;
  return __builtin_amdgcn_perm(ub, ua, 0x07060302u);
}
__device__ __forceinline__ u32t pk2h(float a, float b){
  h16x2 h = { (h16)a, (h16)b };
  return __builtin_bit_cast(u32t, h);
}

// dtype-generic helpers ----------------------------------------------------
template<bool BF>
__device__ __forceinline__ float ldv(const void* p, size_t i){
  if constexpr (BF) return bf2f(((const u16t*)p)[i]);
  else              return ((const float*)p)[i];
}
template<bool BF>
__device__ __forceinline__ void ld8(const void* p, size_t i, float* v){
  if constexpr (BF){
    uint4 u = *(const uint4*)((const u16t*)p + i);
    const u32t a[4] = {u.x, u.y, u.z, u.w};
#pragma unroll
    for (int d = 0; d < 4; ++d){
      v[2*d]   = bf2f((u16t)(a[d] & 0xffffu));
      v[2*d+1] = bf2f((u16t)(a[d] >> 16));
    }
  } else {
    const float4* q = (const float4*)((const float*)p + i);
    float4 A = q[0], B = q[1];
    v[0]=A.x; v[1]=A.y; v[2]=A.z; v[3]=A.w;
    v[4]=B.x; v[5]=B.y; v[6]=B.z; v[7]=B.w;
  }
}

// inline per-wave dtype probe on x[0:128] (wave-uniform, no barrier)
__device__ __forceinline__ bool probe_bf(const void* xv){
  const u16t* p = (const u16t*)xv;
  const int lane = threadIdx.x & 63;
  const u16t h0 = p[lane], h1 = p[lane + 64];
  const int e0 = (h0 >> 7) & 0xff, e1 = (h1 >> 7) & 0xff;
  unsigned long long b0 = __ballot(e0 >= 90 && e0 <= 150);
  unsigned long long b1 = __ballot(e1 >= 90 && e1 <= 150);
  return (__popcll(b0) + __popcll(b1)) >= 104;
}

// ---------------------------------------------------------------------------
// Pre-pass, grid 128 x 1024:
//   bid 0..63 : conv1 + dw3x3 + BN + StarReLU -> t2 (4 channels/block)
//   bid 64..127: W_base -> permuted packed-f16 wbh2
// ---------------------------------------------------------------------------
template<bool BF>
__device__ __forceinline__ void pre12_body(
    const void* x, const void* w, const void* bias,
    const void* dww, const void* dwb,
    const void* bng, const void* bnb, const void* bnm, const void* bnv,
    const void* s1s, const void* s1b, float* t2, float (*ts)[256], int bq)
{
  const int b = bq >> 5, cq = bq & 31;
  const int cl = threadIdx.x >> 8, ij = threadIdx.x & 255;
  const int c = cq * 4 + cl;
  const int i = ij >> 4, j = ij & 15;
  float a0 = ldv<BF>(bias, c);
  const size_t xb = (size_t)b * 65536 + ij;
#pragma unroll 8
  for (int k = 0; k < 256; ++k)
    a0 += ldv<BF>(x, xb + (size_t)k * 256) * ldv<BF>(w, (size_t)c * 256 + k);
  ts[cl][ij] = a0;
  __syncthreads();
  float s = ldv<BF>(dwb, c);
#pragma unroll
  for (int di = 0; di < 3; ++di){
    const int ii = i + di - 1;
    if (ii < 0 || ii > 15) continue;
#pragma unroll
    for (int dj = 0; dj < 3; ++dj){
      const int jj = j + dj - 1;
      if (jj < 0 || jj > 15) continue;
      s += ts[cl][ii * 16 + jj] * ldv<BF>(dww, c * 9 + di * 3 + dj);
    }
  }
  const float v = ldv<BF>(bng, c) * (s - ldv<BF>(bnm, c)) *
                  rsqrtf(ldv<BF>(bnv, c) + 1e-5f) + ldv<BF>(bnb, c);
  const float r = fmaxf(v, 0.0f);
  t2[((size_t)b * 128 + c) * 256 + ij] = ldv<BF>(s1s, 0) * r * r + ldv<BF>(s1b, 0);
}

template<bool BF>
__device__ __forceinline__ void prew_body(const void* wb, uint4* wbh2, int pb){
  const int t = pb * 1024 + threadIdx.x;
  const int e = t & 255, o = t >> 8;
  float v[8];
  ld8<BF>(wb, ((size_t)e * 256 + o) * 8, v);
  wbh2[(size_t)o * 256 + e] = make_uint4(pk2h(v[0], v[1]), pk2h(v[2], v[3]),
                                         pk2h(v[4], v[5]), pk2h(v[6], v[7]));
}

__global__ __launch_bounds__(1024) void k_fused(
    const void* x,
    const void* w1, const void* b1, const void* dww, const void* dwb,
    const void* bng, const void* bnb, const void* bnm, const void* bnv,
    const void* s1s, const void* s1b, const void* wb,
    float* t2, uint4* wbh2)
{
  __shared__ float ts[4][256];
  const bool bf = probe_bf(x);
  const int bid = blockIdx.x;
  if (bid < 64){
    if (bf) pre12_body<true >(x,w1,b1,dww,dwb,bng,bnb,bnm,bnv,s1s,s1b,t2,ts,bid);
    else    pre12_body<false>(x,w1,b1,dww,dwb,bng,bnb,bnm,bnv,s1s,s1b,t2,ts,bid);
  } else {
    if (bf) prew_body<true >(wb, wbh2, bid - 64);
    else    prew_body<false>(wb, wbh2, bid - 64);
  }
}

// ---------------------------------------------------------------------------
// Main hyper-GEMM: grid 512 = (e-half, b, i, j-pair), block 512 = 8 waves.
// 2 blocks/CU (LDS 64.1KB each): block-level overlap of HBM staging vs
// L2/VALU K-loop -- the m114 mechanism the 1-block/CU version lacked.
// E-split: each block computes e in [ec*128, ec*128+128). XCD-paired bids
// (ec at bit3) keep both e-halves of a y patch on one XCD for L2 reuse.
// 4-chunk lookahead-1 pipeline: phase cs = { issue loads cs+1 | compute cs |
// ds_write cs+1 }, one barrier per phase. W single-buffered per ks.
// ---------------------------------------------------------------------------
template<bool BF>
__device__ __forceinline__ void main_body(
    const void* y, const float* t2, const void* cew, const void* ceb,
    const void* s2s, const void* s2b,
    const uint4* wbh2, float* out, u16t* smem)
{
  const int bid = blockIdx.x;
  const int ec  = (bid >> 3) & 1;
  const int gx  = (bid & 7) | ((bid >> 4) << 3);
  const int b = gx >> 7, i = (gx >> 3) & 15, jp = gx & 7, j0 = jp * 2;
  const int tid = threadIdx.x;
  const int wv = tid >> 6, lane = tid & 63;

  // staging thread mapping: w quad, patch row, o-pair-half index
  const int w4 = tid & 3, p = (tid >> 2) & 7, oph = tid >> 5;   // oph 0..15

  // per-chunk staging regs: 2 opq slots x (2x float4 | 2x uint2)
  float fA[2][4], fB[2][4];
  u32t  uA[2][2], uB[2][2];

  auto issue_loads = [&](int cs){
#pragma unroll
    for (int s = 0; s < 2; ++s){
      const int opq = oph + s * 16;
      const int o = (cs * 32 + opq) * 2;                         // even o
      const size_t base = (((size_t)(b * 256 + o) * 128) + i * 8 + p) * 128
                        + jp * 16 + w4 * 4;
      if constexpr (BF){
        const u16t* yp = (const u16t*)y;
        const uint2 u0 = *(const uint2*)(yp + base);
        const uint2 u1 = *(const uint2*)(yp + base + 16384);
        uA[s][0] = u0.x; uA[s][1] = u0.y;
        uB[s][0] = u1.x; uB[s][1] = u1.y;
      } else {
        const float* yp = (const float*)y;
        const float4 A = *(const float4*)(yp + base);
        const float4 B = *(const float4*)(yp + base + 16384);
        fA[s][0]=A.x; fA[s][1]=A.y; fA[s][2]=A.z; fA[s][3]=A.w;
        fB[s][0]=B.x; fB[s][1]=B.y; fB[s][2]=B.z; fB[s][3]=B.w;
      }
    }
  };
  auto write_chunk = [&](int cs){
#pragma unroll
    for (int s = 0; s < 2; ++s){
      u32t pk[4];
      if constexpr (BF){
#pragma unroll
        for (int d = 0; d < 2; ++d){
          const u32t lo = uA[s][d], hi = uB[s][d];
          pk[2*d]   = (lo & 0xffffu) | (hi << 16);
          pk[2*d+1] = (lo >> 16)     | (hi & 0xffff0000u);
        }
      } else {
#pragma unroll
        for (int k = 0; k < 4; ++k) pk[k] = pk2bf(fA[s][k], fB[s][k]);
      }
      const int opq = oph + s * 16;
      const int o  = (cs * 32 + opq) * 2;
      const int oc = o >> 3, osub = o & 7;                       // osub in {0,2,4,6}
#pragma unroll
      for (int k = 0; k < 4; ++k){
        const int w_l  = w4 * 4 + k;
        const int row  = (w_l >> 3) * 64 + p * 8 + (w_l & 7);
        const int phys = (oc + row) & 31;                        // rotation swizzle
        *(u32t*)(smem + row * 256 + phys * 8 + osub) = pk[k];
      }
    }
  };

  // ---- prologue: chunk 0; channel_expand under the latency
  issue_loads(0);

  float* wds = (float*)(smem + 32768);   // 16 floats after the 64KB tile

  // inline channel_expand + StarReLU, 64-lane parallel + shfl reduce
  if (tid < 64){
    const int g = (tid >> 5) & 1, f = (tid >> 2) & 7, cq = tid & 3;
    const int ij = i * 16 + j0 + g;
    const float* tp = t2 + (size_t)b * 32768 + ij;
    float a = 0.0f;
#pragma unroll 8
    for (int c = cq; c < 128; c += 4)
      a += tp[(size_t)c * 256] * ldv<BF>(cew, (size_t)f * 128 + c);
    a += __shfl_xor(a, 1);
    a += __shfl_xor(a, 2);
    if (cq == 0){
      const float tot = a + ldv<BF>(ceb, f);
      const float rr  = fmaxf(tot, 0.0f);
      wds[g * 8 + f] = ldv<BF>(s2s, 0) * rr * rr + ldv<BF>(s2b, 0);
    }
  }

  write_chunk(0);   // compiler inserts the vmcnt wait on chunk-0 loads

  const int l15 = lane & 15, l4 = lane >> 4;
  const int e0  = ec * 128 + wv * 16;

  // W loads: o = ks*32 + l4*8 + r ; idx = o*256 + e0 + l15 (coalesced in l15)
  const uint4* wrow = wbh2 + (size_t)(l4 * 8) * 256 + e0 + l15;

  f32x4 acc[2][4];
#pragma unroll
  for (int g = 0; g < 2; ++g)
#pragma unroll
    for (int nt = 0; nt < 4; ++nt)
      acc[g][nt] = (f32x4){0.f, 0.f, 0.f, 0.f};

  u32t wdp[2][4];

#pragma unroll
  for (int cs = 0; cs < 4; ++cs){
    __syncthreads();                 // chunk cs (and wds at cs==0) now visible
    if (cs == 0){
#pragma unroll
      for (int g = 0; g < 2; ++g)
#pragma unroll
        for (int d = 0; d < 4; ++d)
          wdp[g][d] = pk2h(wds[g * 8 + 2 * d], wds[g * 8 + 2 * d + 1]);
    }
    if (cs < 3) issue_loads(cs + 1);      // loads fly over this phase's compute

    // compute phases ks = 2cs, 2cs+1 from chunk cs (single-buffered W)
#pragma unroll
    for (int kh = 0; kh < 2; ++kh){
      const int ks = cs * 2 + kh;
      uint4 Wb[8];
#pragma unroll
      for (int r = 0; r < 8; ++r) Wb[r] = wrow[(size_t)(ks * 32 + r) * 256];
      float s[2][8];
#pragma unroll
      for (int r = 0; r < 8; ++r){
        const uint4 w4r = Wb[r];
#pragma unroll
        for (int g = 0; g < 2; ++g){
          float t = dot2h(w4r.x, wdp[g][0], 0.0f);
          t = dot2h(w4r.y, wdp[g][1], t);
          t = dot2h(w4r.z, wdp[g][2], t);
          s[g][r] = dot2h(w4r.w, wdp[g][3], t);
        }
      }
#pragma unroll
      for (int g = 0; g < 2; ++g){
        u32t a4[4];
#pragma unroll
        for (int d = 0; d < 4; ++d) a4[d] = pk2bf(s[g][2*d], s[g][2*d+1]);
        const short8 af = __builtin_bit_cast(short8, *(uint4*)a4);
#pragma unroll
        for (int nt = 0; nt < 4; ++nt){
          const int row  = g * 64 + nt * 16 + l15;
          const int phys = (ks * 4 + l4 + row) & 31;
          const short8 bfr = *(const short8*)(smem + row * 256 + phys * 8);
          acc[g][nt] = __builtin_amdgcn_mfma_f32_16x16x32_bf16(af, bfr, acc[g][nt], 0, 0, 0);
        }
      }
    }
    if (cs < 3) write_chunk(cs + 1);      // after compute(cs); before barrier
  }

  // ---- epilogue: C/D layout col=lane&15, row=(lane>>4)*4+reg
#pragma unroll
  for (int g = 0; g < 2; ++g){
#pragma unroll
    for (int nt = 0; nt < 4; ++nt){
      const int col = nt * 16 + l15;
      const int pp = col >> 3, qq = col & 7;
#pragma unroll
      for (int r = 0; r < 4; ++r){
        const int ee = e0 + l4 * 4 + r;
        const size_t oaddr = ((size_t)(b * 256 + ee) * 128 + (i * 8 + pp)) * 128
                           + (j0 + g) * 8 + qq;
        out[oaddr] = acc[g][nt][r];
      }
    }
  }
}
__global__ __launch_bounds__(512, 4) void k_main(
    const void* x, const void* y, const float* t2, const void* cew, const void* ceb,
    const void* s2s, const void* s2b,
    const uint4* wbh2, float* out)
{
  extern __shared__ __align__(16) u16t smem[];
  if (probe_bf(x)) main_body<true >(y, t2, cew, ceb, s2s, s2b, wbh2, out, smem);
  else             main_body<false>(y, t2, cew, ceb, s2s, s2b, wbh2, out, smem);
}

// ---------------------------------------------------------------------------
extern "C" void kernel_launch(void* const* d_in, const int* in_sizes, int n_in,
                              void* d_out, int out_size, void* d_ws, size_t ws_size,
                              hipStream_t stream)
{
  float* t2    = (float*)d_ws;                        // 262144 B
  uint4* wbh2  = (uint4*)((char*)d_ws + 262144);      // 1048576 B

  k_fused<<<dim3(128), dim3(1024), 0, stream>>>(
      d_in[0], d_in[2], d_in[3], d_in[4], d_in[5], d_in[6], d_in[7],
      d_in[8], d_in[9], d_in[10], d_in[11], d_in[16], t2, wbh2);

  const int lds_bytes = 65536 + 64;                   // y tile + 16 wdec floats
  hipFuncSetAttribute((const void*)k_main,
                      hipFuncAttributeMaxDynamicSharedMemorySize, lds_bytes);
  k_main<<<dim3(512), dim3(512), lds_bytes, stream>>>(
      d_in[0], d_in[1], t2, d_in[12], d_in[13], d_in[14], d_in[15],
      wbh2, (float*)d_out);
}